// Round 5
// baseline (295.993 us; speedup 1.0000x reference)
//
#include <hip/hip_runtime.h>

#define N_SAMP 1024
#define XC_DIM 512
#define YC_DIM 256
#define HID_DIM 512
#define TBK 16

// ---------------------------------------------------------------------------
// K1: streaming wave-slab pool. Each wave-iteration: 64 lanes read one
// contiguous 1KB slab (64 float4 = 4 outputs' worth), hsum + 16-lane xor
// shuffle tree (bit-identical reduction order to the R3-passing pool),
// lanes 0/16/32/48 write the 4 outputs. No LDS, no barrier; 2 slabs in
// flight per wave; 8192 blocks = 32/CU queued -> TLP covers latency.
// Also zeroes the gemm2 done-counter (stream order precedes gemm2).
// ---------------------------------------------------------------------------
__global__ __launch_bounds__(256) void pool_kernel(
    const float* __restrict__ x, const float* __restrict__ y,
    float* __restrict__ x_vec, float* __restrict__ y_vec,
    int* __restrict__ counter) {
  if (blockIdx.x == 0 && threadIdx.x == 0) *counter = 0;
  const int w = blockIdx.x * 4 + (threadIdx.x >> 6);  // wave id 0..32767
  const int l = threadIdx.x & 63;
  const float4* xf = (const float4*)x;
  const float4* yf = (const float4*)y;
  // 196608 slabs total: x = 131072 (524288 outputs), y = 65536 (262144).
#pragma unroll
  for (int j = 0; j < 3; ++j) {
    const int s0 = w + (2 * j) * 32768;
    const int s1 = w + (2 * j + 1) * 32768;
    const float4* p0 = (s0 < 131072) ? xf + (long)s0 * 64
                                     : yf + (long)(s0 - 131072) * 64;
    const float4* p1 = (s1 < 131072) ? xf + (long)s1 * 64
                                     : yf + (long)(s1 - 131072) * 64;
    float4 v0 = p0[l];
    float4 v1 = p1[l];
    float h0 = (v0.x + v0.y) + (v0.z + v0.w);
    float h1 = (v1.x + v1.y) + (v1.z + v1.w);
    h0 += __shfl_xor(h0, 1); h1 += __shfl_xor(h1, 1);
    h0 += __shfl_xor(h0, 2); h1 += __shfl_xor(h1, 2);
    h0 += __shfl_xor(h0, 4); h1 += __shfl_xor(h1, 4);
    h0 += __shfl_xor(h0, 8); h1 += __shfl_xor(h1, 8);
    if ((l & 15) == 0) {
      const int g0 = s0 * 4 + (l >> 4);
      const int g1 = s1 * 4 + (l >> 4);
      if (s0 < 131072) x_vec[g0] = h0 * (1.0f / 64.0f);
      else             y_vec[g0 - 524288] = h0 * (1.0f / 64.0f);
      if (s1 < 131072) x_vec[g1] = h1 * (1.0f / 64.0f);
      else             y_vec[g1 - 524288] = h1 * (1.0f / 64.0f);
    }
  }
}

// ---------------------------------------------------------------------------
// K2: Hp[s] = x_vec @ W1[k-chunk s]. 64x64 tile, 4x4/thread, BK=16,
// splitK=4 -> grid (8,16,4) = 512 blocks. Unchanged from R3 (known-good).
// ---------------------------------------------------------------------------
__global__ __launch_bounds__(256) void gemm1_kernel(
    const float* __restrict__ A, const float* __restrict__ B,
    float* __restrict__ Hp) {
  const int K = 512, Nn = 512;
  __shared__ float As[TBK][68];
  __shared__ float Bs[TBK][68];
  const int t = threadIdx.x;
  const int bn = blockIdx.x * 64;
  const int bm = blockIdx.y * 64;
  const int ks = blockIdx.z;          // 0..3, K-chunk of 128

  const int arow = t >> 2, acol = (t & 3) * 4;
  const int brow = t >> 4, bcol = (t & 15) * 4;
  const int row0 = (t >> 4) * 4, col0 = (t & 15) * 4;

  float acc[4][4] = {};
  const int k0 = ks * 128;

  float4 av = *(const float4*)&A[(bm + arow) * K + k0 + acol];
  float4 bv = *(const float4*)&B[(k0 + brow) * Nn + bn + bcol];

  for (int it = 0; it < 8; ++it) {
    __syncthreads();
    As[acol + 0][arow] = av.x;
    As[acol + 1][arow] = av.y;
    As[acol + 2][arow] = av.z;
    As[acol + 3][arow] = av.w;
    *(float4*)&Bs[brow][bcol] = bv;
    __syncthreads();
    if (it < 7) {
      const int k1 = k0 + (it + 1) * TBK;
      av = *(const float4*)&A[(bm + arow) * K + k1 + acol];
      bv = *(const float4*)&B[(k1 + brow) * Nn + bn + bcol];
    }
#pragma unroll
    for (int kk = 0; kk < TBK; ++kk) {
      float4 a = *(const float4*)&As[kk][row0];
      float4 b = *(const float4*)&Bs[kk][col0];
      acc[0][0] += a.x * b.x; acc[0][1] += a.x * b.y; acc[0][2] += a.x * b.z; acc[0][3] += a.x * b.w;
      acc[1][0] += a.y * b.x; acc[1][1] += a.y * b.y; acc[1][2] += a.y * b.z; acc[1][3] += a.y * b.w;
      acc[2][0] += a.z * b.x; acc[2][1] += a.z * b.y; acc[2][2] += a.z * b.z; acc[2][3] += a.z * b.w;
      acc[3][0] += a.w * b.x; acc[3][1] += a.w * b.y; acc[3][2] += a.w * b.z; acc[3][3] += a.w * b.w;
    }
  }

  float* H = Hp + (long)ks * (N_SAMP * HID_DIM);
#pragma unroll
  for (int i = 0; i < 4; ++i) {
    float4 o;
    o.x = acc[i][0]; o.y = acc[i][1]; o.z = acc[i][2]; o.w = acc[i][3];
    *(float4*)&H[(long)(bm + row0 + i) * Nn + bn + col0] = o;
  }
}

// ---------------------------------------------------------------------------
// K3: gemm2 + fused reductions + LAST-BLOCK finalize.
// Partials as in R3 (cs_part, ycs_part, dot_part). Then: threadfence ->
// one atomicAdd on counter (device scope) -> block seeing old==511 runs the
// R3 finalize body. Data-driven; no dispatch-order/coherence assumption
// beyond device-scope atomics + fences (guide G12/G16).
// ---------------------------------------------------------------------------
__global__ __launch_bounds__(256) void gemm2_kernel(
    const float* __restrict__ Hp, const float* __restrict__ b1,
    const float* __restrict__ B, const float* __restrict__ yv,
    float* __restrict__ cs_part, float* __restrict__ ycs_part,
    float* __restrict__ dot_part, int* __restrict__ counter,
    const float* __restrict__ b2, float* __restrict__ out) {
  const int K = 512, Nn = 256;
  __shared__ float As[TBK][68];
  __shared__ float Bs[TBK][68];
  __shared__ float redd[4];
  __shared__ float red2[3][4];
  __shared__ int lastFlag;
  const int t = threadIdx.x;
  const int bn = blockIdx.x * 64;
  const int bm = blockIdx.y * 64;
  const int ks = blockIdx.z;          // 0..7, K-chunk of 64
  const long HS = (long)N_SAMP * HID_DIM;

  const int arow = t >> 2, acol = (t & 3) * 4;
  const int brow = t >> 4, bcol = (t & 15) * 4;
  const int row0 = (t >> 4) * 4, col0 = (t & 15) * 4;

  float acc[4][4] = {};
  const int k0 = ks * 64;

  long aidx = (long)(bm + arow) * K + k0 + acol;
  float4 a0 = *(const float4*)&Hp[aidx];
  float4 a1 = *(const float4*)&Hp[aidx + HS];
  float4 a2 = *(const float4*)&Hp[aidx + 2 * HS];
  float4 a3 = *(const float4*)&Hp[aidx + 3 * HS];
  float4 bb = *(const float4*)&b1[k0 + acol];
  float4 bv = *(const float4*)&B[(k0 + brow) * Nn + bn + bcol];

  for (int it = 0; it < 4; ++it) {
    float4 av;
    av.x = fmaxf(a0.x + a1.x + a2.x + a3.x + bb.x, 0.0f);
    av.y = fmaxf(a0.y + a1.y + a2.y + a3.y + bb.y, 0.0f);
    av.z = fmaxf(a0.z + a1.z + a2.z + a3.z + bb.z, 0.0f);
    av.w = fmaxf(a0.w + a1.w + a2.w + a3.w + bb.w, 0.0f);
    __syncthreads();
    As[acol + 0][arow] = av.x;
    As[acol + 1][arow] = av.y;
    As[acol + 2][arow] = av.z;
    As[acol + 3][arow] = av.w;
    *(float4*)&Bs[brow][bcol] = bv;
    __syncthreads();
    if (it < 3) {
      const int k1 = k0 + (it + 1) * TBK;
      aidx = (long)(bm + arow) * K + k1 + acol;
      a0 = *(const float4*)&Hp[aidx];
      a1 = *(const float4*)&Hp[aidx + HS];
      a2 = *(const float4*)&Hp[aidx + 2 * HS];
      a3 = *(const float4*)&Hp[aidx + 3 * HS];
      bb = *(const float4*)&b1[k1 + acol];
      bv = *(const float4*)&B[(k1 + brow) * Nn + bn + bcol];
    }
#pragma unroll
    for (int kk = 0; kk < TBK; ++kk) {
      float4 a = *(const float4*)&As[kk][row0];
      float4 b = *(const float4*)&Bs[kk][col0];
      acc[0][0] += a.x * b.x; acc[0][1] += a.x * b.y; acc[0][2] += a.x * b.z; acc[0][3] += a.x * b.w;
      acc[1][0] += a.y * b.x; acc[1][1] += a.y * b.y; acc[1][2] += a.y * b.z; acc[1][3] += a.y * b.w;
      acc[2][0] += a.z * b.x; acc[2][1] += a.z * b.y; acc[2][2] += a.z * b.z; acc[2][3] += a.z * b.w;
      acc[3][0] += a.w * b.x; acc[3][1] += a.w * b.y; acc[3][2] += a.w * b.z; acc[3][3] += a.w * b.w;
    }
  }

  // ---- fused epilogue: dot(acc, y-tile), colsum(acc), colsum(y-tile) ----
  float dp = 0.f;
  float cmu0 = 0.f, cmu1 = 0.f, cmu2 = 0.f, cmu3 = 0.f;
  float cy0 = 0.f, cy1 = 0.f, cy2 = 0.f, cy3 = 0.f;
#pragma unroll
  for (int i = 0; i < 4; ++i) {
    const float4 yy = *(const float4*)&yv[(long)(bm + row0 + i) * Nn + bn + col0];
    dp += acc[i][0] * yy.x + acc[i][1] * yy.y + acc[i][2] * yy.z + acc[i][3] * yy.w;
    cmu0 += acc[i][0]; cmu1 += acc[i][1]; cmu2 += acc[i][2]; cmu3 += acc[i][3];
    cy0 += yy.x; cy1 += yy.y; cy2 += yy.z; cy3 += yy.w;
  }
#pragma unroll
  for (int off = 1; off < 64; off <<= 1) dp += __shfl_xor(dp, off);

  __syncthreads();  // all threads done reading As/Bs -> safe to reuse
  {
    float4 o; o.x = cmu0; o.y = cmu1; o.z = cmu2; o.w = cmu3;
    *(float4*)&As[t >> 4][col0] = o;
    float4 q; q.x = cy0; q.y = cy1; q.z = cy2; q.w = cy3;
    *(float4*)&Bs[t >> 4][col0] = q;
  }
  if ((t & 63) == 0) redd[t >> 6] = dp;
  __syncthreads();

  const int bid = blockIdx.x + 4 * blockIdx.y + 64 * blockIdx.z;
  if (t < 64) {
    float s = 0.f;
#pragma unroll
    for (int g = 0; g < 16; ++g) s += As[g][t];
    cs_part[(blockIdx.y * 8 + ks) * 256 + bn + t] = s;
  } else if (t < 128) {
    if (ks == 0) {
      const int c = t - 64;
      float s = 0.f;
#pragma unroll
      for (int g = 0; g < 16; ++g) s += Bs[g][c];
      ycs_part[blockIdx.y * 256 + bn + c] = s;
    }
  } else if (t == 128) {
    dot_part[bid] = redd[0] + redd[1] + redd[2] + redd[3];
  }

  // ---- last-block finalize ----
  __threadfence();          // release: all this block's partial stores
  __syncthreads();
  if (t == 0) lastFlag = (atomicAdd(counter, 1) == 511);
  __syncthreads();
  if (lastFlag) {
    __threadfence();        // acquire: see all other blocks' partials
    const float b2d = b2[t];
    float cm = 1024.0f * b2d;
#pragma unroll 8
    for (int p = 0; p < 128; ++p) cm += cs_part[p * 256 + t];
    float cy = 0.f;
#pragma unroll
    for (int p = 0; p < 16; ++p) cy += ycs_part[p * 256 + t];
    float v1 = cm * cy;              // sum_d cm*cy
    float v2 = b2d * cy;             // b2 dot-term
    float v3 = dot_part[t] + dot_part[t + 256];
#pragma unroll
    for (int off = 1; off < 64; off <<= 1) {
      v1 += __shfl_xor(v1, off);
      v2 += __shfl_xor(v2, off);
      v3 += __shfl_xor(v3, off);
    }
    if ((t & 63) == 0) {
      red2[0][t >> 6] = v1; red2[1][t >> 6] = v2; red2[2][t >> 6] = v3;
    }
    __syncthreads();
    if (t == 0) {
      float S1 = red2[0][0] + red2[0][1] + red2[0][2] + red2[0][3];
      float S2 = red2[1][0] + red2[1][1] + red2[1][2] + red2[1][3];
      float S0 = red2[2][0] + red2[2][1] + red2[2][2] + red2[2][3];
      float dot = S0 + S2;
      out[0] = dot * (1.0f / 1024.0f) - S1 * (1.0f / (1024.0f * 1024.0f));
    }
  }
}

// ---------------------------------------------------------------------------
extern "C" void kernel_launch(void* const* d_in, const int* in_sizes, int n_in,
                              void* d_out, int out_size, void* d_ws, size_t ws_size,
                              hipStream_t stream) {
  const float* x  = (const float*)d_in[0];
  const float* y  = (const float*)d_in[1];
  const float* W1 = (const float*)d_in[2];
  const float* b1 = (const float*)d_in[3];
  const float* W2 = (const float*)d_in[4];
  const float* b2 = (const float*)d_in[5];
  float* out = (float*)d_out;

  char* ws = (char*)d_ws;
  float* x_vec = (float*)ws;                        // 2 MB
  float* y_vec = (float*)(ws + (2lu << 20));        // 1 MB
  float* Hp    = (float*)(ws + (4lu << 20));        // 4 x 2 MB = 8 MB
  float* cs_part  = (float*)(ws + (12lu << 20));            // 128*256*4 = 128 KB
  float* ycs_part = (float*)(ws + (12lu << 20) + (160lu << 10)); // 16 KB
  float* dot_part = (float*)(ws + (12lu << 20) + (192lu << 10)); // 2 KB
  int*   counter  = (int*)  (ws + (12lu << 20) + (224lu << 10)); // 4 B

  pool_kernel<<<8192, 256, 0, stream>>>(x, y, x_vec, y_vec, counter);

  gemm1_kernel<<<dim3(8, 16, 4), 256, 0, stream>>>(x_vec, W1, Hp);

  gemm2_kernel<<<dim3(4, 16, 8), 256, 0, stream>>>(Hp, b1, W2, y_vec,
                                                   cs_part, ycs_part, dot_part,
                                                   counter, b2, out);
}

// Round 6
// 289.247 us; speedup vs baseline: 1.0233x; 1.0233x over previous
//
#include <hip/hip_runtime.h>

#define N_SAMP 1024
#define XC_DIM 512
#define YC_DIM 256
#define HID_DIM 512
#define TBK 16

// ---------------------------------------------------------------------------
// K1: fused spatial pooling — R3's proven version (261.3us total), restored
// byte-for-byte after R5's wave-slab variant regressed the total by +35us.
// 2 loads/thread, 32 outputs/block, 24576 blocks. Also zeroes the gemm2
// done-counter (block 0; stream order precedes gemm2).
// ---------------------------------------------------------------------------
__global__ __launch_bounds__(256) void pool_kernel(
    const float* __restrict__ x, const float* __restrict__ y,
    float* __restrict__ x_vec, float* __restrict__ y_vec,
    int* __restrict__ counter) {
  if (blockIdx.x == 0 && threadIdx.x == 0) *counter = 0;
  __shared__ float s[16 * 33];  // [k][o] k=0..15, o=0..31 (pad 33)
  const int t = threadIdx.x;
  const long blk = blockIdx.x;
  const float4* src;
  float* dst;
  long obase;
  if (blk < 16384) {           // x: 524288 outputs / 32 = 16384 blocks
    src = (const float4*)x; dst = x_vec; obase = blk * 32;
  } else {                     // y: 262144 outputs / 32 = 8192 blocks
    src = (const float4*)y; dst = y_vec; obase = (blk - 16384) * 32;
  }
  const float4* p = src + obase * 16;  // 512 float4 per block

  float4 v0 = p[t];
  float4 v1 = p[t + 256];
  float h0 = (v0.x + v0.y) + (v0.z + v0.w);
  float h1 = (v1.x + v1.y) + (v1.z + v1.w);

  s[(t & 15) * 33 + (t >> 4)] = h0;
  s[(t & 15) * 33 + 16 + (t >> 4)] = h1;
  __syncthreads();

  const int o = t >> 3;        // 0..31
  const int r = t & 7;
  float dp = s[(2 * r) * 33 + o] + s[(2 * r + 1) * 33 + o];
#pragma unroll
  for (int off = 1; off < 8; off <<= 1) dp += __shfl_xor(dp, off);
  if (r == 0) dst[obase + o] = dp * (1.0f / 64.0f);
}

// ---------------------------------------------------------------------------
// K2: Hp[s] = x_vec @ W1[k-chunk s]. 64x64 tile, 4x4/thread, BK=16,
// splitK=4 -> grid (8,16,4) = 512 blocks. Unchanged from R3 (known-good).
// ---------------------------------------------------------------------------
__global__ __launch_bounds__(256) void gemm1_kernel(
    const float* __restrict__ A, const float* __restrict__ B,
    float* __restrict__ Hp) {
  const int K = 512, Nn = 512;
  __shared__ float As[TBK][68];
  __shared__ float Bs[TBK][68];
  const int t = threadIdx.x;
  const int bn = blockIdx.x * 64;
  const int bm = blockIdx.y * 64;
  const int ks = blockIdx.z;          // 0..3, K-chunk of 128

  const int arow = t >> 2, acol = (t & 3) * 4;
  const int brow = t >> 4, bcol = (t & 15) * 4;
  const int row0 = (t >> 4) * 4, col0 = (t & 15) * 4;

  float acc[4][4] = {};
  const int k0 = ks * 128;

  float4 av = *(const float4*)&A[(bm + arow) * K + k0 + acol];
  float4 bv = *(const float4*)&B[(k0 + brow) * Nn + bn + bcol];

  for (int it = 0; it < 8; ++it) {
    __syncthreads();
    As[acol + 0][arow] = av.x;
    As[acol + 1][arow] = av.y;
    As[acol + 2][arow] = av.z;
    As[acol + 3][arow] = av.w;
    *(float4*)&Bs[brow][bcol] = bv;
    __syncthreads();
    if (it < 7) {
      const int k1 = k0 + (it + 1) * TBK;
      av = *(const float4*)&A[(bm + arow) * K + k1 + acol];
      bv = *(const float4*)&B[(k1 + brow) * Nn + bn + bcol];
    }
#pragma unroll
    for (int kk = 0; kk < TBK; ++kk) {
      float4 a = *(const float4*)&As[kk][row0];
      float4 b = *(const float4*)&Bs[kk][col0];
      acc[0][0] += a.x * b.x; acc[0][1] += a.x * b.y; acc[0][2] += a.x * b.z; acc[0][3] += a.x * b.w;
      acc[1][0] += a.y * b.x; acc[1][1] += a.y * b.y; acc[1][2] += a.y * b.z; acc[1][3] += a.y * b.w;
      acc[2][0] += a.z * b.x; acc[2][1] += a.z * b.y; acc[2][2] += a.z * b.z; acc[2][3] += a.z * b.w;
      acc[3][0] += a.w * b.x; acc[3][1] += a.w * b.y; acc[3][2] += a.w * b.z; acc[3][3] += a.w * b.w;
    }
  }

  float* H = Hp + (long)ks * (N_SAMP * HID_DIM);
#pragma unroll
  for (int i = 0; i < 4; ++i) {
    float4 o;
    o.x = acc[i][0]; o.y = acc[i][1]; o.z = acc[i][2]; o.w = acc[i][3];
    *(float4*)&H[(long)(bm + row0 + i) * Nn + bn + col0] = o;
  }
}

// ---------------------------------------------------------------------------
// K3: gemm2 + fused reductions (R3's exact arithmetic) + last-block finalize
// (R5's tail, verbatim — it passed absmax 0.0). 511 blocks exit after one
// device-scope atomicAdd; the last block runs finalize. No dispatch-order
// or coherence assumption beyond device-scope atomics + fences (G12/G16).
// ---------------------------------------------------------------------------
__global__ __launch_bounds__(256) void gemm2_kernel(
    const float* __restrict__ Hp, const float* __restrict__ b1,
    const float* __restrict__ B, const float* __restrict__ yv,
    float* __restrict__ cs_part, float* __restrict__ ycs_part,
    float* __restrict__ dot_part, int* __restrict__ counter,
    const float* __restrict__ b2, float* __restrict__ out) {
  const int K = 512, Nn = 256;
  __shared__ float As[TBK][68];
  __shared__ float Bs[TBK][68];
  __shared__ float redd[4];
  __shared__ float red2[3][4];
  __shared__ int lastFlag;
  const int t = threadIdx.x;
  const int bn = blockIdx.x * 64;
  const int bm = blockIdx.y * 64;
  const int ks = blockIdx.z;          // 0..7, K-chunk of 64
  const long HS = (long)N_SAMP * HID_DIM;

  const int arow = t >> 2, acol = (t & 3) * 4;
  const int brow = t >> 4, bcol = (t & 15) * 4;
  const int row0 = (t >> 4) * 4, col0 = (t & 15) * 4;

  float acc[4][4] = {};
  const int k0 = ks * 64;

  long aidx = (long)(bm + arow) * K + k0 + acol;
  float4 a0 = *(const float4*)&Hp[aidx];
  float4 a1 = *(const float4*)&Hp[aidx + HS];
  float4 a2 = *(const float4*)&Hp[aidx + 2 * HS];
  float4 a3 = *(const float4*)&Hp[aidx + 3 * HS];
  float4 bb = *(const float4*)&b1[k0 + acol];
  float4 bv = *(const float4*)&B[(k0 + brow) * Nn + bn + bcol];

  for (int it = 0; it < 4; ++it) {
    float4 av;
    av.x = fmaxf(a0.x + a1.x + a2.x + a3.x + bb.x, 0.0f);
    av.y = fmaxf(a0.y + a1.y + a2.y + a3.y + bb.y, 0.0f);
    av.z = fmaxf(a0.z + a1.z + a2.z + a3.z + bb.z, 0.0f);
    av.w = fmaxf(a0.w + a1.w + a2.w + a3.w + bb.w, 0.0f);
    __syncthreads();
    As[acol + 0][arow] = av.x;
    As[acol + 1][arow] = av.y;
    As[acol + 2][arow] = av.z;
    As[acol + 3][arow] = av.w;
    *(float4*)&Bs[brow][bcol] = bv;
    __syncthreads();
    if (it < 3) {
      const int k1 = k0 + (it + 1) * TBK;
      aidx = (long)(bm + arow) * K + k1 + acol;
      a0 = *(const float4*)&Hp[aidx];
      a1 = *(const float4*)&Hp[aidx + HS];
      a2 = *(const float4*)&Hp[aidx + 2 * HS];
      a3 = *(const float4*)&Hp[aidx + 3 * HS];
      bb = *(const float4*)&b1[k1 + acol];
      bv = *(const float4*)&B[(k1 + brow) * Nn + bn + bcol];
    }
#pragma unroll
    for (int kk = 0; kk < TBK; ++kk) {
      float4 a = *(const float4*)&As[kk][row0];
      float4 b = *(const float4*)&Bs[kk][col0];
      acc[0][0] += a.x * b.x; acc[0][1] += a.x * b.y; acc[0][2] += a.x * b.z; acc[0][3] += a.x * b.w;
      acc[1][0] += a.y * b.x; acc[1][1] += a.y * b.y; acc[1][2] += a.y * b.z; acc[1][3] += a.y * b.w;
      acc[2][0] += a.z * b.x; acc[2][1] += a.z * b.y; acc[2][2] += a.z * b.z; acc[2][3] += a.z * b.w;
      acc[3][0] += a.w * b.x; acc[3][1] += a.w * b.y; acc[3][2] += a.w * b.z; acc[3][3] += a.w * b.w;
    }
  }

  // ---- fused epilogue: dot(acc, y-tile), colsum(acc), colsum(y-tile) ----
  float dp = 0.f;
  float cmu0 = 0.f, cmu1 = 0.f, cmu2 = 0.f, cmu3 = 0.f;
  float cy0 = 0.f, cy1 = 0.f, cy2 = 0.f, cy3 = 0.f;
#pragma unroll
  for (int i = 0; i < 4; ++i) {
    const float4 yy = *(const float4*)&yv[(long)(bm + row0 + i) * Nn + bn + col0];
    dp += acc[i][0] * yy.x + acc[i][1] * yy.y + acc[i][2] * yy.z + acc[i][3] * yy.w;
    cmu0 += acc[i][0]; cmu1 += acc[i][1]; cmu2 += acc[i][2]; cmu3 += acc[i][3];
    cy0 += yy.x; cy1 += yy.y; cy2 += yy.z; cy3 += yy.w;
  }
#pragma unroll
  for (int off = 1; off < 64; off <<= 1) dp += __shfl_xor(dp, off);

  __syncthreads();  // all threads done reading As/Bs -> safe to reuse
  {
    float4 o; o.x = cmu0; o.y = cmu1; o.z = cmu2; o.w = cmu3;
    *(float4*)&As[t >> 4][col0] = o;
    float4 q; q.x = cy0; q.y = cy1; q.z = cy2; q.w = cy3;
    *(float4*)&Bs[t >> 4][col0] = q;
  }
  if ((t & 63) == 0) redd[t >> 6] = dp;
  __syncthreads();

  const int bid = blockIdx.x + 4 * blockIdx.y + 64 * blockIdx.z;
  if (t < 64) {
    float s = 0.f;
#pragma unroll
    for (int g = 0; g < 16; ++g) s += As[g][t];
    cs_part[(blockIdx.y * 8 + ks) * 256 + bn + t] = s;
  } else if (t < 128) {
    if (ks == 0) {
      const int c = t - 64;
      float s = 0.f;
#pragma unroll
      for (int g = 0; g < 16; ++g) s += Bs[g][c];
      ycs_part[blockIdx.y * 256 + bn + c] = s;
    }
  } else if (t == 128) {
    dot_part[bid] = redd[0] + redd[1] + redd[2] + redd[3];
  }

  // ---- last-block finalize ----
  __threadfence();          // release: all this block's partial stores
  __syncthreads();
  if (t == 0) lastFlag = (atomicAdd(counter, 1) == 511);
  __syncthreads();
  if (lastFlag) {
    __threadfence();        // acquire: see all other blocks' partials
    const float b2d = b2[t];
    float cm = 1024.0f * b2d;
#pragma unroll 8
    for (int p = 0; p < 128; ++p) cm += cs_part[p * 256 + t];
    float cy = 0.f;
#pragma unroll
    for (int p = 0; p < 16; ++p) cy += ycs_part[p * 256 + t];
    float v1 = cm * cy;              // sum_d cm*cy
    float v2 = b2d * cy;             // b2 dot-term
    float v3 = dot_part[t] + dot_part[t + 256];
#pragma unroll
    for (int off = 1; off < 64; off <<= 1) {
      v1 += __shfl_xor(v1, off);
      v2 += __shfl_xor(v2, off);
      v3 += __shfl_xor(v3, off);
    }
    if ((t & 63) == 0) {
      red2[0][t >> 6] = v1; red2[1][t >> 6] = v2; red2[2][t >> 6] = v3;
    }
    __syncthreads();
    if (t == 0) {
      float S1 = red2[0][0] + red2[0][1] + red2[0][2] + red2[0][3];
      float S2 = red2[1][0] + red2[1][1] + red2[1][2] + red2[1][3];
      float S0 = red2[2][0] + red2[2][1] + red2[2][2] + red2[2][3];
      float dot = S0 + S2;
      out[0] = dot * (1.0f / 1024.0f) - S1 * (1.0f / (1024.0f * 1024.0f));
    }
  }
}

// ---------------------------------------------------------------------------
extern "C" void kernel_launch(void* const* d_in, const int* in_sizes, int n_in,
                              void* d_out, int out_size, void* d_ws, size_t ws_size,
                              hipStream_t stream) {
  const float* x  = (const float*)d_in[0];
  const float* y  = (const float*)d_in[1];
  const float* W1 = (const float*)d_in[2];
  const float* b1 = (const float*)d_in[3];
  const float* W2 = (const float*)d_in[4];
  const float* b2 = (const float*)d_in[5];
  float* out = (float*)d_out;

  char* ws = (char*)d_ws;
  float* x_vec = (float*)ws;                        // 2 MB
  float* y_vec = (float*)(ws + (2lu << 20));        // 1 MB
  float* Hp    = (float*)(ws + (4lu << 20));        // 4 x 2 MB = 8 MB
  float* cs_part  = (float*)(ws + (12lu << 20));            // 128*256*4 = 128 KB
  float* ycs_part = (float*)(ws + (12lu << 20) + (160lu << 10)); // 16 KB
  float* dot_part = (float*)(ws + (12lu << 20) + (192lu << 10)); // 2 KB
  int*   counter  = (int*)  (ws + (12lu << 20) + (224lu << 10)); // 4 B

  pool_kernel<<<24576, 256, 0, stream>>>(x, y, x_vec, y_vec, counter);

  gemm1_kernel<<<dim3(8, 16, 4), 256, 0, stream>>>(x_vec, W1, Hp);

  gemm2_kernel<<<dim3(4, 16, 8), 256, 0, stream>>>(Hp, b1, W2, y_vec,
                                                   cs_part, ycs_part, dot_part,
                                                   counter, b2, out);
}

// Round 7
// 260.732 us; speedup vs baseline: 1.1352x; 1.1094x over previous
//
#include <hip/hip_runtime.h>

#define N_SAMP 1024
#define XC_DIM 512
#define YC_DIM 256
#define HID_DIM 512
#define TBK 16

// ---------------------------------------------------------------------------
// K1: spatial pooling, barrier-free single-round wave-slab form.
// Strictly dominates both prior variants: no LDS/barrier (vs R3 pool), no
// serial per-wave loop (vs R5 pool). Each wave: 2 independent float4 loads
// per lane covering a contiguous 2KB slab-pair (block reads 16KB contiguous),
// hsum + 4-step 16-lane xor shuffle tree (reduction order identical to the
// R5 pool, which passed absmax 0.0), lanes 0/16/32/48 write 4+4 outputs.
// 24576 blocks = 96/CU -> TLP covers latency; one round, no chain.
// ---------------------------------------------------------------------------
__global__ __launch_bounds__(256) void pool_kernel(
    const float* __restrict__ x, const float* __restrict__ y,
    float* __restrict__ x_vec, float* __restrict__ y_vec) {
  const int t = threadIdx.x;
  const int w = t >> 6;        // wave 0..3
  const int l = t & 63;
  const long blk = blockIdx.x;
  const float4* src;
  float* dst;
  long sbase;
  if (blk < 16384) {           // x: 131072 slabs = 16384 blocks * 8
    src = (const float4*)x; dst = x_vec; sbase = blk * 8;
  } else {                     // y: 65536 slabs = 8192 blocks * 8
    src = (const float4*)y; dst = y_vec; sbase = (blk - 16384) * 8;
  }
  const long s0 = sbase + w * 2;    // consecutive slab pair per wave
  const long s1 = s0 + 1;

  float4 v0 = src[s0 * 64 + l];
  float4 v1 = src[s1 * 64 + l];
  float h0 = (v0.x + v0.y) + (v0.z + v0.w);
  float h1 = (v1.x + v1.y) + (v1.z + v1.w);
  h0 += __shfl_xor(h0, 1); h1 += __shfl_xor(h1, 1);
  h0 += __shfl_xor(h0, 2); h1 += __shfl_xor(h1, 2);
  h0 += __shfl_xor(h0, 4); h1 += __shfl_xor(h1, 4);
  h0 += __shfl_xor(h0, 8); h1 += __shfl_xor(h1, 8);
  if ((l & 15) == 0) {
    dst[s0 * 4 + (l >> 4)] = h0 * (1.0f / 64.0f);
    dst[s1 * 4 + (l >> 4)] = h1 * (1.0f / 64.0f);
  }
}

// ---------------------------------------------------------------------------
// K2: Hp[s] = x_vec @ W1[k-chunk s]. 64x64 tile, 4x4/thread, BK=16,
// splitK=4 -> grid (8,16,4) = 512 blocks. Unchanged from R3 (known-good).
// ---------------------------------------------------------------------------
__global__ __launch_bounds__(256) void gemm1_kernel(
    const float* __restrict__ A, const float* __restrict__ B,
    float* __restrict__ Hp) {
  const int K = 512, Nn = 512;
  __shared__ float As[TBK][68];
  __shared__ float Bs[TBK][68];
  const int t = threadIdx.x;
  const int bn = blockIdx.x * 64;
  const int bm = blockIdx.y * 64;
  const int ks = blockIdx.z;          // 0..3, K-chunk of 128

  const int arow = t >> 2, acol = (t & 3) * 4;
  const int brow = t >> 4, bcol = (t & 15) * 4;
  const int row0 = (t >> 4) * 4, col0 = (t & 15) * 4;

  float acc[4][4] = {};
  const int k0 = ks * 128;

  float4 av = *(const float4*)&A[(bm + arow) * K + k0 + acol];
  float4 bv = *(const float4*)&B[(k0 + brow) * Nn + bn + bcol];

  for (int it = 0; it < 8; ++it) {
    __syncthreads();
    As[acol + 0][arow] = av.x;
    As[acol + 1][arow] = av.y;
    As[acol + 2][arow] = av.z;
    As[acol + 3][arow] = av.w;
    *(float4*)&Bs[brow][bcol] = bv;
    __syncthreads();
    if (it < 7) {
      const int k1 = k0 + (it + 1) * TBK;
      av = *(const float4*)&A[(bm + arow) * K + k1 + acol];
      bv = *(const float4*)&B[(k1 + brow) * Nn + bn + bcol];
    }
#pragma unroll
    for (int kk = 0; kk < TBK; ++kk) {
      float4 a = *(const float4*)&As[kk][row0];
      float4 b = *(const float4*)&Bs[kk][col0];
      acc[0][0] += a.x * b.x; acc[0][1] += a.x * b.y; acc[0][2] += a.x * b.z; acc[0][3] += a.x * b.w;
      acc[1][0] += a.y * b.x; acc[1][1] += a.y * b.y; acc[1][2] += a.y * b.z; acc[1][3] += a.y * b.w;
      acc[2][0] += a.z * b.x; acc[2][1] += a.z * b.y; acc[2][2] += a.z * b.z; acc[2][3] += a.z * b.w;
      acc[3][0] += a.w * b.x; acc[3][1] += a.w * b.y; acc[3][2] += a.w * b.z; acc[3][3] += a.w * b.w;
    }
  }

  float* H = Hp + (long)ks * (N_SAMP * HID_DIM);
#pragma unroll
  for (int i = 0; i < 4; ++i) {
    float4 o;
    o.x = acc[i][0]; o.y = acc[i][1]; o.z = acc[i][2]; o.w = acc[i][3];
    *(float4*)&H[(long)(bm + row0 + i) * Nn + bn + col0] = o;
  }
}

// ---------------------------------------------------------------------------
// K3: gemm2 + fused reductions (R3 exact — no counter, no fences; R6 showed
// device-scope fence sync costs ~28us on gfx950's non-coherent L2s).
// ---------------------------------------------------------------------------
__global__ __launch_bounds__(256) void gemm2_kernel(
    const float* __restrict__ Hp, const float* __restrict__ b1,
    const float* __restrict__ B, const float* __restrict__ yv,
    float* __restrict__ cs_part, float* __restrict__ ycs_part,
    float* __restrict__ dot_part) {
  const int K = 512, Nn = 256;
  __shared__ float As[TBK][68];
  __shared__ float Bs[TBK][68];
  __shared__ float redd[4];
  const int t = threadIdx.x;
  const int bn = blockIdx.x * 64;
  const int bm = blockIdx.y * 64;
  const int ks = blockIdx.z;          // 0..7, K-chunk of 64
  const long HS = (long)N_SAMP * HID_DIM;

  const int arow = t >> 2, acol = (t & 3) * 4;
  const int brow = t >> 4, bcol = (t & 15) * 4;
  const int row0 = (t >> 4) * 4, col0 = (t & 15) * 4;

  float acc[4][4] = {};
  const int k0 = ks * 64;

  long aidx = (long)(bm + arow) * K + k0 + acol;
  float4 a0 = *(const float4*)&Hp[aidx];
  float4 a1 = *(const float4*)&Hp[aidx + HS];
  float4 a2 = *(const float4*)&Hp[aidx + 2 * HS];
  float4 a3 = *(const float4*)&Hp[aidx + 3 * HS];
  float4 bb = *(const float4*)&b1[k0 + acol];
  float4 bv = *(const float4*)&B[(k0 + brow) * Nn + bn + bcol];

  for (int it = 0; it < 4; ++it) {
    float4 av;
    av.x = fmaxf(a0.x + a1.x + a2.x + a3.x + bb.x, 0.0f);
    av.y = fmaxf(a0.y + a1.y + a2.y + a3.y + bb.y, 0.0f);
    av.z = fmaxf(a0.z + a1.z + a2.z + a3.z + bb.z, 0.0f);
    av.w = fmaxf(a0.w + a1.w + a2.w + a3.w + bb.w, 0.0f);
    __syncthreads();
    As[acol + 0][arow] = av.x;
    As[acol + 1][arow] = av.y;
    As[acol + 2][arow] = av.z;
    As[acol + 3][arow] = av.w;
    *(float4*)&Bs[brow][bcol] = bv;
    __syncthreads();
    if (it < 3) {
      const int k1 = k0 + (it + 1) * TBK;
      aidx = (long)(bm + arow) * K + k1 + acol;
      a0 = *(const float4*)&Hp[aidx];
      a1 = *(const float4*)&Hp[aidx + HS];
      a2 = *(const float4*)&Hp[aidx + 2 * HS];
      a3 = *(const float4*)&Hp[aidx + 3 * HS];
      bb = *(const float4*)&b1[k1 + acol];
      bv = *(const float4*)&B[(k1 + brow) * Nn + bn + bcol];
    }
#pragma unroll
    for (int kk = 0; kk < TBK; ++kk) {
      float4 a = *(const float4*)&As[kk][row0];
      float4 b = *(const float4*)&Bs[kk][col0];
      acc[0][0] += a.x * b.x; acc[0][1] += a.x * b.y; acc[0][2] += a.x * b.z; acc[0][3] += a.x * b.w;
      acc[1][0] += a.y * b.x; acc[1][1] += a.y * b.y; acc[1][2] += a.y * b.z; acc[1][3] += a.y * b.w;
      acc[2][0] += a.z * b.x; acc[2][1] += a.z * b.y; acc[2][2] += a.z * b.z; acc[2][3] += a.z * b.w;
      acc[3][0] += a.w * b.x; acc[3][1] += a.w * b.y; acc[3][2] += a.w * b.z; acc[3][3] += a.w * b.w;
    }
  }

  // ---- fused epilogue: dot(acc, y-tile), colsum(acc), colsum(y-tile) ----
  float dp = 0.f;
  float cmu0 = 0.f, cmu1 = 0.f, cmu2 = 0.f, cmu3 = 0.f;
  float cy0 = 0.f, cy1 = 0.f, cy2 = 0.f, cy3 = 0.f;
#pragma unroll
  for (int i = 0; i < 4; ++i) {
    const float4 yy = *(const float4*)&yv[(long)(bm + row0 + i) * Nn + bn + col0];
    dp += acc[i][0] * yy.x + acc[i][1] * yy.y + acc[i][2] * yy.z + acc[i][3] * yy.w;
    cmu0 += acc[i][0]; cmu1 += acc[i][1]; cmu2 += acc[i][2]; cmu3 += acc[i][3];
    cy0 += yy.x; cy1 += yy.y; cy2 += yy.z; cy3 += yy.w;
  }
#pragma unroll
  for (int off = 1; off < 64; off <<= 1) dp += __shfl_xor(dp, off);

  __syncthreads();  // all threads done reading As/Bs -> safe to reuse
  {
    float4 o; o.x = cmu0; o.y = cmu1; o.z = cmu2; o.w = cmu3;
    *(float4*)&As[t >> 4][col0] = o;
    float4 q; q.x = cy0; q.y = cy1; q.z = cy2; q.w = cy3;
    *(float4*)&Bs[t >> 4][col0] = q;
  }
  if ((t & 63) == 0) redd[t >> 6] = dp;
  __syncthreads();

  const int bid = blockIdx.x + 4 * blockIdx.y + 64 * blockIdx.z;
  if (t < 64) {
    float s = 0.f;
#pragma unroll
    for (int g = 0; g < 16; ++g) s += As[g][t];
    cs_part[(blockIdx.y * 8 + ks) * 256 + bn + t] = s;
  } else if (t < 128) {
    if (ks == 0) {
      const int c = t - 64;
      float s = 0.f;
#pragma unroll
      for (int g = 0; g < 16; ++g) s += Bs[g][c];
      ycs_part[blockIdx.y * 256 + bn + c] = s;
    }
  } else if (t == 128) {
    dot_part[bid] = redd[0] + redd[1] + redd[2] + redd[3];
  }
}

// ---------------------------------------------------------------------------
// K4: finalize (R3 exact).
// ---------------------------------------------------------------------------
__global__ __launch_bounds__(256) void finalize_kernel(
    const float* __restrict__ cs_part, const float* __restrict__ ycs_part,
    const float* __restrict__ dot_part, const float* __restrict__ b2,
    float* __restrict__ out) {
  __shared__ float red[3][4];
  const int t = threadIdx.x;  // = d
  const float b2d = b2[t];
  float cm = 1024.0f * b2d;
#pragma unroll 8
  for (int p = 0; p < 128; ++p) cm += cs_part[p * 256 + t];
  float cy = 0.f;
#pragma unroll
  for (int p = 0; p < 16; ++p) cy += ycs_part[p * 256 + t];
  float v1 = cm * cy;              // for sum_d cm*cy
  float v2 = b2d * cy;             // for b2 dot-term
  float v3 = dot_part[t] + dot_part[t + 256];
#pragma unroll
  for (int off = 1; off < 64; off <<= 1) {
    v1 += __shfl_xor(v1, off);
    v2 += __shfl_xor(v2, off);
    v3 += __shfl_xor(v3, off);
  }
  if ((t & 63) == 0) {
    red[0][t >> 6] = v1; red[1][t >> 6] = v2; red[2][t >> 6] = v3;
  }
  __syncthreads();
  if (t == 0) {
    float S1 = red[0][0] + red[0][1] + red[0][2] + red[0][3];
    float S2 = red[1][0] + red[1][1] + red[1][2] + red[1][3];
    float S0 = red[2][0] + red[2][1] + red[2][2] + red[2][3];
    float dot = S0 + S2;
    out[0] = dot * (1.0f / 1024.0f) - S1 * (1.0f / (1024.0f * 1024.0f));
  }
}

// ---------------------------------------------------------------------------
extern "C" void kernel_launch(void* const* d_in, const int* in_sizes, int n_in,
                              void* d_out, int out_size, void* d_ws, size_t ws_size,
                              hipStream_t stream) {
  const float* x  = (const float*)d_in[0];
  const float* y  = (const float*)d_in[1];
  const float* W1 = (const float*)d_in[2];
  const float* b1 = (const float*)d_in[3];
  const float* W2 = (const float*)d_in[4];
  const float* b2 = (const float*)d_in[5];
  float* out = (float*)d_out;

  char* ws = (char*)d_ws;
  float* x_vec = (float*)ws;                        // 2 MB
  float* y_vec = (float*)(ws + (2lu << 20));        // 1 MB
  float* Hp    = (float*)(ws + (4lu << 20));        // 4 x 2 MB = 8 MB
  float* cs_part  = (float*)(ws + (12lu << 20));            // 128*256*4 = 128 KB
  float* ycs_part = (float*)(ws + (12lu << 20) + (160lu << 10)); // 16 KB
  float* dot_part = (float*)(ws + (12lu << 20) + (192lu << 10)); // 2 KB

  pool_kernel<<<24576, 256, 0, stream>>>(x, y, x_vec, y_vec);

  gemm1_kernel<<<dim3(8, 16, 4), 256, 0, stream>>>(x_vec, W1, Hp);

  gemm2_kernel<<<dim3(4, 16, 8), 256, 0, stream>>>(Hp, b1, W2, y_vec,
                                                   cs_part, ycs_part, dot_part);

  finalize_kernel<<<1, 256, 0, stream>>>(cs_part, ycs_part, dot_part, b2, out);
}